// Round 1
// baseline (590.970 us; speedup 1.0000x reference)
//
#include <hip/hip_runtime.h>
#include <math.h>

// QLSTM collapse: gates depend only on row 0 of each W_gate, and cx/hx are
// constant across the H dimension (broadcast of a scalar recurrence).
//   A[t,b,g]   = inputs[t,b,:] . v_g + d_g          (precomputed projection)
//   x0_g       = A[t,b,g] + hval[b] * c_g
//   gate       = sigmoid(cos(x0_g) * cos(th_g[0]))
//   cval       = f*cval + i*g ; hval = o*tanh(cval)
//   ys[t,b,:]  = hval ; hx[b,:] = hval_final ; cx[b,:] = cval_final

constexpr int TT = 512;   // time
constexpr int BB = 256;   // batch
constexpr int DD = 512;   // input dim
constexpr int HH = 512;   // hidden dim
// NQ = 8

// ---------------- prep: fold weights into v_g[512], c_g, d_g, cos(th_g) ----
__global__ void prep_kernel(const float* __restrict__ W_itq, const float* __restrict__ b_itq,
                            const float* __restrict__ W_in, const float* __restrict__ th_in,
                            const float* __restrict__ W_fg, const float* __restrict__ th_fg,
                            const float* __restrict__ W_up, const float* __restrict__ th_up,
                            const float* __restrict__ W_out, const float* __restrict__ th_out,
                            float* __restrict__ V, float* __restrict__ C) {
    int d = threadIdx.x;            // 0..511
    float vi = 0.f, vf = 0.f, vu = 0.f, vo = 0.f;
    #pragma unroll
    for (int n = 0; n < 8; ++n) {
        float w = W_itq[n * (DD + HH) + d];   // input-part column d
        vi += w * W_in[n];                    // W_gate[0][n] = W_gate[n]
        vf += w * W_fg[n];
        vu += w * W_up[n];
        vo += w * W_out[n];
    }
    V[0 * DD + d] = vi;
    V[1 * DD + d] = vf;
    V[2 * DD + d] = vu;
    V[3 * DD + d] = vo;

    // Wh_sum[n] = sum_h W_itq[n][D+h] ; 8 waves, wave wv handles n=wv
    __shared__ float whsum[8];
    int wv = d >> 6, lane = d & 63;
    float s = 0.f;
    for (int h = lane; h < HH; h += 64) s += W_itq[wv * (DD + HH) + DD + h];
    #pragma unroll
    for (int off = 32; off > 0; off >>= 1) s += __shfl_down(s, off);
    if (lane == 0) whsum[wv] = s;
    __syncthreads();

    if (d < 4) {
        const float* Wg = (d == 0) ? W_in : (d == 1) ? W_fg : (d == 2) ? W_up : W_out;
        const float* th = (d == 0) ? th_in : (d == 1) ? th_fg : (d == 2) ? th_up : th_out;
        float c = 0.f, dg = 0.f;
        #pragma unroll
        for (int n = 0; n < 8; ++n) {
            c  += whsum[n] * Wg[n];
            dg += b_itq[n] * Wg[n];
        }
        C[d]     = c;            // c_g  (hval coefficient)
        C[4 + d] = cosf(th[0]);  // cos(theta_g[0])
        C[8 + d] = dg;           // d_g  (bias term, folded into A)
    }
}

// ---------------- proj: A[r][g] = x[r,:] . v_g + d_g  (r = t*B+b) ----------
__global__ void __launch_bounds__(256) proj_kernel(const float* __restrict__ x,
                                                   const float* __restrict__ V,
                                                   const float* __restrict__ C,
                                                   float* __restrict__ A) {
    int lane = threadIdx.x & 63;

    // per-lane constant fragments of v_g: lane owns elements [4*lane..4*lane+3]
    // and [256+4*lane..256+4*lane+3]; kept in registers (no LDS).
    float4 v0[4], v1[4];
    #pragma unroll
    for (int g = 0; g < 4; ++g) {
        const float4* vg = (const float4*)(V + g * DD);
        v0[g] = vg[lane];
        v1[g] = vg[64 + lane];
    }
    float dg[4];
    #pragma unroll
    for (int g = 0; g < 4; ++g) dg[g] = C[8 + g];

    int wid = (int)((blockIdx.x * 256u + threadIdx.x) >> 6);
    int nw  = (int)((gridDim.x * 256u) >> 6);
    for (int r = wid; r < TT * BB; r += nw) {
        const float4* xr = (const float4*)(x + (size_t)r * DD);
        float4 a0 = xr[lane];        // coalesced: elements 4*lane..
        float4 a1 = xr[64 + lane];   // coalesced: elements 256+4*lane..
        float p[4];
        #pragma unroll
        for (int g = 0; g < 4; ++g) {
            p[g] = a0.x * v0[g].x + a0.y * v0[g].y + a0.z * v0[g].z + a0.w * v0[g].w
                 + a1.x * v1[g].x + a1.y * v1[g].y + a1.z * v1[g].z + a1.w * v1[g].w;
        }
        #pragma unroll
        for (int off = 32; off > 0; off >>= 1) {
            #pragma unroll
            for (int g = 0; g < 4; ++g) p[g] += __shfl_down(p[g], off);
        }
        if (lane == 0) {
            float4 o = make_float4(p[0] + dg[0], p[1] + dg[1], p[2] + dg[2], p[3] + dg[3]);
            ((float4*)A)[r] = o;
        }
    }
}

// ---------------- scan: 256 scalar chains over T=512 steps -----------------
__global__ void scan_kernel(const float* __restrict__ A, const float* __restrict__ C,
                            float* __restrict__ hv, float* __restrict__ cfin) {
    int b = threadIdx.x;             // one thread per batch element
    float c0 = C[0], c1 = C[1], c2 = C[2], c3 = C[3];
    float q0 = C[4], q1 = C[5], q2 = C[6], q3 = C[7];
    float hval = 0.f, cval = 0.f;
    const float4* A4 = (const float4*)A;
    #pragma unroll 2
    for (int t = 0; t < TT; ++t) {
        float4 a = A4[t * BB + b];   // coalesced across b
        float zi = __cosf(__fmaf_rn(hval, c0, a.x)) * q0;
        float zf = __cosf(__fmaf_rn(hval, c1, a.y)) * q1;
        float zu = __cosf(__fmaf_rn(hval, c2, a.z)) * q2;
        float zo = __cosf(__fmaf_rn(hval, c3, a.w)) * q3;
        float gi = __builtin_amdgcn_rcpf(1.f + __expf(-zi));
        float gf = __builtin_amdgcn_rcpf(1.f + __expf(-zf));
        float gu = __builtin_amdgcn_rcpf(1.f + __expf(-zu));
        float go = __builtin_amdgcn_rcpf(1.f + __expf(-zo));
        cval = __fmaf_rn(gf, cval, gi * gu);
        // tanh(c) = 1 - 2/(exp(2c)+1)
        float e  = __expf(2.f * cval);
        float th = 1.f - 2.f * __builtin_amdgcn_rcpf(e + 1.f);
        hval = go * th;
        hv[t * BB + b] = hval;
    }
    cfin[b] = cval;
}

// ---------------- bcast: ys[t,b,:] = hv[t,b]; hx/cx rows -------------------
__global__ void __launch_bounds__(256) bcast_kernel(const float* __restrict__ hv,
                                                    const float* __restrict__ cfin,
                                                    float* __restrict__ out) {
    int wid  = (int)((blockIdx.x * 256u + threadIdx.x) >> 6);
    int lane = threadIdx.x & 63;
    int nw   = (int)((gridDim.x * 256u) >> 6);
    const int nrow = TT * BB + 2 * BB;   // ys rows + hx rows + cx rows
    for (int r = wid; r < nrow; r += nw) {
        float val;
        if (r < TT * BB)           val = hv[r];
        else if (r < TT * BB + BB) val = hv[(TT - 1) * BB + (r - TT * BB)];
        else                       val = cfin[r - TT * BB - BB];
        float4 v = make_float4(val, val, val, val);
        float4* o = (float4*)(out + (size_t)r * HH);
        o[lane]      = v;    // 64 lanes x 16B = 1 KB contiguous
        o[64 + lane] = v;    // second 1 KB of the 2 KB row
    }
}

extern "C" void kernel_launch(void* const* d_in, const int* in_sizes, int n_in,
                              void* d_out, int out_size, void* d_ws, size_t ws_size,
                              hipStream_t stream) {
    const float* x     = (const float*)d_in[0];
    const float* W_itq = (const float*)d_in[1];
    const float* b_itq = (const float*)d_in[2];
    const float* W_in  = (const float*)d_in[3];
    const float* th_in = (const float*)d_in[4];
    const float* W_fg  = (const float*)d_in[5];
    const float* th_fg = (const float*)d_in[6];
    const float* W_up  = (const float*)d_in[7];
    const float* th_up = (const float*)d_in[8];
    const float* W_out = (const float*)d_in[9];
    const float* th_out= (const float*)d_in[10];
    float* out = (float*)d_out;

    // workspace layout (floats): V[2048] | C[12] (pad) | A[T*B*4] | hv[T*B] | cfin[B]
    float* ws   = (float*)d_ws;
    float* V    = ws;                 // 4 x 512
    float* C    = ws + 2048;          // 12 consts
    float* A    = ws + 4096;          // 16 KB offset, 16B aligned
    float* hv   = A + TT * BB * 4;    // T*B
    float* cfin = hv + TT * BB;       // B

    prep_kernel<<<1, 512, 0, stream>>>(W_itq, b_itq, W_in, th_in, W_fg, th_fg,
                                       W_up, th_up, W_out, th_out, V, C);
    proj_kernel<<<2048, 256, 0, stream>>>(x, V, C, A);
    scan_kernel<<<1, BB, 0, stream>>>(A, C, hv, cfin);
    bcast_kernel<<<2048, 256, 0, stream>>>(hv, cfin, out);
}

// Round 4
// 534.526 us; speedup vs baseline: 1.1056x; 1.1056x over previous
//
#include <hip/hip_runtime.h>
#include <math.h>

// QLSTM collapse: gates depend only on row 0 of each W_gate, and cx/hx are
// constant across the H dimension (broadcast of a scalar recurrence).
//   A[t,b,g]   = inputs[t,b,:] . v_g + d_g          (precomputed projection)
//   x0_g       = A[t,b,g] + hval[b] * c_g
//   gate       = sigmoid(cos(x0_g) * cos(th_g[0]))
//   cval       = f*cval + i*g ; hval = o*tanh(cval)
//   ys[t,b,:]  = hval ; hx[b,:] = hval_final ; cx[b,:] = cval_final

constexpr int TT = 512;   // time
constexpr int BB = 256;   // batch
constexpr int DD = 512;   // input dim
constexpr int HH = 512;   // hidden dim
// NQ = 8

#define LOG2E 1.44269504088896340736f
#define EXP2F(x) __builtin_amdgcn_exp2f(x)   // v_exp_f32: 2^x (HIP has no __exp2f)

// ---------------- prep: fold weights into v_g[512], c_g, q2_g, d_g ---------
__global__ void prep_kernel(const float* __restrict__ W_itq, const float* __restrict__ b_itq,
                            const float* __restrict__ W_in, const float* __restrict__ th_in,
                            const float* __restrict__ W_fg, const float* __restrict__ th_fg,
                            const float* __restrict__ W_up, const float* __restrict__ th_up,
                            const float* __restrict__ W_out, const float* __restrict__ th_out,
                            float* __restrict__ V, float* __restrict__ C) {
    int d = threadIdx.x;            // 0..511
    float vi = 0.f, vf = 0.f, vu = 0.f, vo = 0.f;
    #pragma unroll
    for (int n = 0; n < 8; ++n) {
        float w = W_itq[n * (DD + HH) + d];   // input-part column d
        vi += w * W_in[n];                    // W_gate[0][n] = W_gate[n]
        vf += w * W_fg[n];
        vu += w * W_up[n];
        vo += w * W_out[n];
    }
    V[0 * DD + d] = vi;
    V[1 * DD + d] = vf;
    V[2 * DD + d] = vu;
    V[3 * DD + d] = vo;

    // Wh_sum[n] = sum_h W_itq[n][D+h] ; 8 waves, wave wv handles n=wv
    __shared__ float whsum[8];
    int wv = d >> 6, lane = d & 63;
    float s = 0.f;
    for (int h = lane; h < HH; h += 64) s += W_itq[wv * (DD + HH) + DD + h];
    #pragma unroll
    for (int off = 32; off > 0; off >>= 1) s += __shfl_down(s, off);
    if (lane == 0) whsum[wv] = s;
    __syncthreads();

    if (d < 4) {
        const float* Wg = (d == 0) ? W_in : (d == 1) ? W_fg : (d == 2) ? W_up : W_out;
        const float* th = (d == 0) ? th_in : (d == 1) ? th_fg : (d == 2) ? th_up : th_out;
        float c = 0.f, dg = 0.f;
        #pragma unroll
        for (int n = 0; n < 8; ++n) {
            c  += whsum[n] * Wg[n];
            dg += b_itq[n] * Wg[n];
        }
        C[d]     = c;                         // c_g (hval coefficient)
        C[4 + d] = -cosf(th[0]) * LOG2E;      // q2_g: sigmoid(z*cos th) = 1/(1+2^(z*q2))
        C[8 + d] = dg;                        // d_g (bias, folded into A)
    }
}

// ---------------- proj: A[r][g] = x[r,:] . v_g + d_g  (r = t*B+b) ----------
__global__ void __launch_bounds__(256) proj_kernel(const float* __restrict__ x,
                                                   const float* __restrict__ V,
                                                   const float* __restrict__ C,
                                                   float* __restrict__ A) {
    int lane = threadIdx.x & 63;

    // per-lane constant fragments of v_g: lane owns elements [4*lane..4*lane+3]
    // and [256+4*lane..256+4*lane+3]; kept in registers (no LDS).
    float4 v0[4], v1[4];
    #pragma unroll
    for (int g = 0; g < 4; ++g) {
        const float4* vg = (const float4*)(V + g * DD);
        v0[g] = vg[lane];
        v1[g] = vg[64 + lane];
    }
    float dg[4];
    #pragma unroll
    for (int g = 0; g < 4; ++g) dg[g] = C[8 + g];

    int wid = (int)((blockIdx.x * 256u + threadIdx.x) >> 6);
    int nw  = (int)((gridDim.x * 256u) >> 6);
    for (int r = wid; r < TT * BB; r += nw) {
        const float4* xr = (const float4*)(x + (size_t)r * DD);
        float4 a0 = xr[lane];        // coalesced: elements 4*lane..
        float4 a1 = xr[64 + lane];   // coalesced: elements 256+4*lane..
        float p[4];
        #pragma unroll
        for (int g = 0; g < 4; ++g) {
            p[g] = a0.x * v0[g].x + a0.y * v0[g].y + a0.z * v0[g].z + a0.w * v0[g].w
                 + a1.x * v1[g].x + a1.y * v1[g].y + a1.z * v1[g].z + a1.w * v1[g].w;
        }
        #pragma unroll
        for (int off = 32; off > 0; off >>= 1) {
            #pragma unroll
            for (int g = 0; g < 4; ++g) p[g] += __shfl_down(p[g], off);
        }
        if (lane == 0) {
            float4 o = make_float4(p[0] + dg[0], p[1] + dg[1], p[2] + dg[2], p[3] + dg[3]);
            ((float4*)A)[r] = o;
        }
    }
}

// ---------------- scan: 256 scalar chains over T=512 steps -----------------
// 4 blocks x 64 lanes (4 CUs). Software-pipelined A loads, depth 8, fully
// static register indices (runtime-indexed reg arrays spill to scratch).
__global__ void __launch_bounds__(64, 1) scan_kernel(const float* __restrict__ A,
                                                     const float* __restrict__ C,
                                                     float* __restrict__ hv,
                                                     float* __restrict__ cfin) {
    int b = blockIdx.x * 64 + threadIdx.x;    // one thread per batch chain
    float c0 = C[0], c1 = C[1], c2 = C[2], c3 = C[3];
    float q0 = C[4], q1 = C[5], q2 = C[6], q3 = C[7];
    float hval = 0.f, cval = 0.f;
    const float4* A4 = (const float4*)A;

    float4 buf[8];
    #pragma unroll
    for (int j = 0; j < 8; ++j) buf[j] = A4[j * BB + b];

    for (int tg = 0; tg < TT; tg += 8) {
        // issue next group's loads first (8 outstanding, hides ~900cy miss)
        float4 nxt[8];
        #pragma unroll
        for (int j = 0; j < 8; ++j) {
            int tt = tg + 8 + j; if (tt > TT - 1) tt = TT - 1;   // clamp (tail unused)
            nxt[j] = A4[tt * BB + b];
        }
        #pragma unroll
        for (int j = 0; j < 8; ++j) {
            float4 a = buf[j];
            // gate = 1/(1+2^(cos(x)*q2)),  q2 = -cos(th)*log2(e)
            float gi = __builtin_amdgcn_rcpf(1.f + EXP2F(__cosf(__fmaf_rn(hval, c0, a.x)) * q0));
            float gf = __builtin_amdgcn_rcpf(1.f + EXP2F(__cosf(__fmaf_rn(hval, c1, a.y)) * q1));
            float gu = __builtin_amdgcn_rcpf(1.f + EXP2F(__cosf(__fmaf_rn(hval, c2, a.z)) * q2));
            float go = __builtin_amdgcn_rcpf(1.f + EXP2F(__cosf(__fmaf_rn(hval, c3, a.w)) * q3));
            cval = __fmaf_rn(gf, cval, gi * gu);
            // tanh(c) = 1 - 2/(1 + 2^(2c*log2e))
            float e  = EXP2F(cval * (2.f * LOG2E));
            float th = __fmaf_rn(-2.f, __builtin_amdgcn_rcpf(e + 1.f), 1.f);
            hval = go * th;
            hv[(tg + j) * BB + b] = hval;
        }
        #pragma unroll
        for (int j = 0; j < 8; ++j) buf[j] = nxt[j];
    }
    cfin[b] = cval;
}

// ---------------- bcast: ys[t,b,:] = hv[t,b]; hx/cx rows -------------------
__global__ void __launch_bounds__(256) bcast_kernel(const float* __restrict__ hv,
                                                    const float* __restrict__ cfin,
                                                    float* __restrict__ out) {
    int wid  = (int)((blockIdx.x * 256u + threadIdx.x) >> 6);
    int lane = threadIdx.x & 63;
    int nw   = (int)((gridDim.x * 256u) >> 6);
    const int nrow = TT * BB + 2 * BB;   // ys rows + hx rows + cx rows
    for (int r = wid; r < nrow; r += nw) {
        float val;
        if (r < TT * BB)           val = hv[r];
        else if (r < TT * BB + BB) val = hv[(TT - 1) * BB + (r - TT * BB)];
        else                       val = cfin[r - TT * BB - BB];
        float4 v = make_float4(val, val, val, val);
        float4* o = (float4*)(out + (size_t)r * HH);
        o[lane]      = v;    // 64 lanes x 16B = 1 KB contiguous
        o[64 + lane] = v;    // second 1 KB of the 2 KB row
    }
}

extern "C" void kernel_launch(void* const* d_in, const int* in_sizes, int n_in,
                              void* d_out, int out_size, void* d_ws, size_t ws_size,
                              hipStream_t stream) {
    const float* x     = (const float*)d_in[0];
    const float* W_itq = (const float*)d_in[1];
    const float* b_itq = (const float*)d_in[2];
    const float* W_in  = (const float*)d_in[3];
    const float* th_in = (const float*)d_in[4];
    const float* W_fg  = (const float*)d_in[5];
    const float* th_fg = (const float*)d_in[6];
    const float* W_up  = (const float*)d_in[7];
    const float* th_up = (const float*)d_in[8];
    const float* W_out = (const float*)d_in[9];
    const float* th_out= (const float*)d_in[10];
    float* out = (float*)d_out;

    // workspace layout (floats): V[2048] | C[12] (pad) | A[T*B*4] | hv[T*B] | cfin[B]
    float* ws   = (float*)d_ws;
    float* V    = ws;                 // 4 x 512
    float* C    = ws + 2048;          // 12 consts
    float* A    = ws + 4096;          // 16 KB offset, 16B aligned
    float* hv   = A + TT * BB * 4;    // T*B
    float* cfin = hv + TT * BB;       // B

    prep_kernel<<<1, 512, 0, stream>>>(W_itq, b_itq, W_in, th_in, W_fg, th_fg,
                                       W_up, th_up, W_out, th_out, V, C);
    proj_kernel<<<2048, 256, 0, stream>>>(x, V, C, A);
    scan_kernel<<<4, 64, 0, stream>>>(A, C, hv, cfin);
    bcast_kernel<<<2048, 256, 0, stream>>>(hv, cfin, out);
}